// Round 4
// baseline (1005.776 us; speedup 1.0000x reference)
//
#include <hip/hip_runtime.h>
#include <math.h>

#define IMG   160
#define HWSZ  25600
#define NB    4
#define CIN   256
#define COUT1 384
#define BIGK  90000

// output offsets (in floats)
#define OFF_LMAP 0
#define OFF_JMAP 102400
#define OFF_JOFF 204800
#define OFF_CMAP 409600
#define OFF_COFF 512000
#define OFF_LVEC 716800
#define OFF_LOI  1126400
#define OFF_MASK 1206400

// workspace offsets (bytes)
static const size_t WS_Y1    = 0;
static const size_t WS_JSORT = (size_t)NB * COUT1 * HWSZ * 4;            // 157286400
static const size_t WS_CSORT = WS_JSORT + (size_t)NB * 32768 * 8;        // contiguous!
static const size_t WS_JUNC  = WS_CSORT + (size_t)NB * 32768 * 8;
static const size_t WS_JVAL  = WS_JUNC + (size_t)NB * 300 * 2 * 4;
static const size_t WS_LKEY  = WS_JVAL + (size_t)NB * 300 * 4;
static const size_t WS_WPK   = WS_LKEY + (size_t)NB * 8192 * 4;
// Wpack: 12 octiles * 8 icc * 9 taps * 32 ocl * 64 shorts * 2 B = 3,538,944
static const size_t WS_AFTER_WPK = WS_WPK + (size_t)12 * 8 * 9 * 32 * 64 * 2;
static const size_t WS_BNS   = WS_AFTER_WPK;                             // 384 f32
static const size_t WS_JM    = WS_BNS + 384 * 4;                         // NB*300 u64
static const size_t WS_CM    = WS_JM + (size_t)NB * 300 * 8;             // NB*5000 u64
static const size_t WS_FPK   = WS_CM + (size_t)NB * 5000 * 8;
static const size_t WS_NEED_MIN = WS_FPK;                                // legacy floor
// packed feat: [b][icc 8][py 162][px 162][128 B]  (zero border, slot-swizzled)
static const size_t WS_NEED_PK = WS_FPK + (size_t)NB * 8 * 162 * 162 * 128;  // ~258 MB

typedef unsigned long long u64;
typedef __attribute__((ext_vector_type(8))) short short8;
typedef __attribute__((ext_vector_type(4))) float f32x4;
typedef __attribute__((ext_vector_type(4))) int int4v;

union frag_u { short8 s8; u64 u[2]; int4v v; };

__device__ __forceinline__ float clip_coord(float v) {
    return fminf(fmaxf(v, 0.0f), 159.9999f);
}
__device__ __forceinline__ float sigmoidf(float v) {
    return 1.0f / (1.0f + expf(-v));
}
__device__ __forceinline__ unsigned short f2bf(float f) {   // RNE
    unsigned u = __float_as_uint(f);
    return (unsigned short)((u + 0x7FFFu + ((u >> 16) & 1u)) >> 16);
}
__device__ __forceinline__ float bf2f(unsigned short h) {
    return __uint_as_float((unsigned)h << 16);
}

// async 16B global -> LDS (DMA). LDS dest must be wave-uniform base; HW adds lane*16.
__device__ __forceinline__ void async_copy16(void* lds, const void* g) {
    __builtin_amdgcn_global_load_lds(
        (const __attribute__((address_space(1))) unsigned int*)g,
        (__attribute__((address_space(3))) unsigned int*)lds, 16, 0, 0);
}

// ===========================================================================
// ============================  NEW (pk) PATH  ==============================
// ===========================================================================

// ---------------------------------------------------------------------------
// Fused preprocessing: wpack (blocks 0..6911) + bnscale (6912) +
// pack_feat (6913..20034).  One launch instead of three.
//
// Wpack[octile 12][icc 8][tap 9][ocl 32][8 phys 16B-slots][8 shorts]
//   phys slot p16 holds LOGICAL slot p16 ^ (ocl & 7);
//   logical slot l16 = t*4+quad -> term t, channels quad*8..+7 (k-order)
// fpk[b][icc][py 162][px 162][128 B]: phys slot p holds logical p ^ s,
//   s = (2*py+px)&7; logical l: term t=l>>2, channels (l&3)*8..+7.
// ---------------------------------------------------------------------------
__global__ __launch_bounds__(256) void prep_kernel(
    const float* __restrict__ w1, short* __restrict__ wpk,
    const float* __restrict__ gamma, const float* __restrict__ var,
    float* __restrict__ bns,
    const float* __restrict__ feat, short* __restrict__ fpk) {
    const int blk = blockIdx.x;
    const int tid = threadIdx.x;
    if (blk < 6912) {                        // ---- wpack
        int e = blk * 256 + tid;             // 1,769,472 exact
        int row = e >> 6, sp = e & 63;
        int ocl = row & 31;
        int tap = (row >> 5) % 9;
        int icc = (row / 288) & 7;
        int octile = row / 2304;
        int p16 = sp >> 3, j = sp & 7;
        int l16 = p16 ^ (ocl & 7);           // logical 16B slot
        int ql = l16 * 8 + j;                // logical short index 0..63
        int term = ql >> 5, icl = ql & 31;
        int oc = octile * 32 + ocl, ic = icc * 32 + icl;
        float a = w1[((size_t)oc * CIN + ic) * 9 + tap];
        unsigned short hi = f2bf(a);
        wpk[e] = (term == 0) ? (short)hi : (short)f2bf(a - bf2f(hi));
        return;
    }
    if (blk == 6912) {                       // ---- bnscale (bitwise-same expr)
        for (int i = tid; i < COUT1; i += 256)
            bns[i] = gamma[i] / sqrtf(var[i] + 1e-5f);
        return;
    }
    // ---- pack_feat
    const int c4  = (tid >> 4) & 3;                       // channel quarter 0..3
    const int r0  = (tid & 15) | (((tid >> 6) & 3) << 4); // 0..63
    const int rest = (blk - 6913) * 64 + r0;  // (b*8+icc)*26244 + py*162 + px
    const int px = rest % 162;
    const int t2 = rest / 162;
    const int py = t2 % 162;
    const int bi = t2 / 162;                 // b*8 + icc
    const int s  = (2 * py + px) & 7;
    const int gy = py - 1, gx = px - 1;
    const bool valid = ((unsigned)gy < (unsigned)IMG) && ((unsigned)gx < (unsigned)IMG);
    const float* fs = feat + (size_t)(bi * 32 + c4 * 8) * HWSZ
                           + (valid ? gy * IMG + gx : 0);
    unsigned hi4[4], lo4[4];
#pragma unroll
    for (int j2 = 0; j2 < 4; ++j2) {
        float va = valid ? fs[(size_t)(2 * j2) * HWSZ]     : 0.0f;
        float vb = valid ? fs[(size_t)(2 * j2 + 1) * HWSZ] : 0.0f;
        unsigned short ha = f2bf(va), hb = f2bf(vb);
        unsigned short la = f2bf(va - bf2f(ha)), lb = f2bf(vb - bf2f(hb));
        hi4[j2] = (unsigned)ha | ((unsigned)hb << 16);
        lo4[j2] = (unsigned)la | ((unsigned)lb << 16);
    }
    const int p0 = c4 ^ s;            // phys slot of logical l=c4 (term0)
    const int p1 = (c4 | 4) ^ s;      // phys slot of logical l=c4+4 (term1)
    int4v* base = (int4v*)(fpk + (size_t)rest * 64);
    base[p0] = (int4v){ (int)hi4[0], (int)hi4[1], (int)hi4[2], (int)hi4[3] };
    base[p1] = (int4v){ (int)lo4[0], (int)lo4[1], (int)lo4[2], (int)lo4[3] };
}

// ---------------------------------------------------------------------------
// conv1 via MFMA implicit GEMM, 3-product bf16 split.  16x32 px tile,
// 8 waves, 1 block/CU.  A double-buffered: A(icc+1) DMA issues at compute
// start into the idle buffer (latency hidden under ~8400cyc MFMA);
// B(icc+1) reg-prefetched the same way; write phase is pure ds_writes.
// Per-px accumulation order identical to rounds 2/3 -> bitwise-identical y1.
// ---------------------------------------------------------------------------
__global__ __launch_bounds__(512, 2) void conv1_mfma_pk(
    const short* __restrict__ fpk, const short* __restrict__ wpk,
    const float* __restrict__ b1, const float* __restrict__ bns,
    const float* __restrict__ beta, const float* __restrict__ mean,
    float* __restrict__ y1) {
    const int bid   = blockIdx.x;                 // 0..2399
    const int slot  = bid >> 3;                   // 0..299
    const int tile  = (bid & 7) + ((slot / 12) << 3);   // XCD-local tile set
    const int octile = slot - (slot / 12) * 12;   // 0..11
    const int bb = tile / 50, tt = tile % 50;
    const int ty = (tt / 5) * 16, tx = (tt % 5) * 32;
    const int oc0 = octile * 32;
    const int tid  = threadIdx.x;
    const int wid  = tid >> 6;              // 0..7
    const int wr   = wid >> 1;              // px row group (4 rows)
    const int wc   = wid & 1;               // px col group (16 cols)
    const int lane = tid & 63;
    const int quad = lane >> 4;
    const int l15  = lane & 15;
    const int wbase = tid & ~63;            // wave-uniform

    __shared__ __align__(16) short Alds[2][288 * 64];  // 2 x 36864 B
    __shared__ __align__(16) short Blds[612 * 64];     // 78336 B (18 x 34 pos)

    int aoff[2];
#pragma unroll
    for (int t = 0; t < 2; ++t)
        aoff[t] = l15 * 128 + ((((t << 2) | quad) ^ (l15 & 7)) << 4);

    f32x4 acc[2][4];
#pragma unroll
    for (int mi = 0; mi < 2; ++mi)
#pragma unroll
        for (int nj = 0; nj < 4; ++nj) acc[mi][nj] = (f32x4){0.f, 0.f, 0.f, 0.f};

    const char* asrc0 = (const char*)wpk + (size_t)(octile * 8) * 36864;

    // B geometry: 18 rows x 272 16B-chunks (4352 B/row), 4896 chunks total
    int boff[10];
#pragma unroll
    for (int it = 0; it < 10; ++it) {
        int k = it * 512 + tid;
        int hy = (int)((unsigned)k / 272u);
        int r  = k - hy * 272;
        boff[it] = hy * (162 * 128) + r * 16;
    }
    const char* bsrc0 = (const char*)fpk
        + (((size_t)(bb * 8) * 162 + ty) * 162 + tx) * 128;
    const size_t bstride = (size_t)162 * 162 * 128;   // per-icc stride

    // ---- prologue: stage A(0) + B(0) via DMA
    {
        char* ad = (char*)&Alds[0][0];
#pragma unroll
        for (int i = 0; i < 4; ++i)
            async_copy16(ad + (size_t)(i * 512 + wbase) * 16,
                         asrc0 + (size_t)(i * 512 + tid) * 16);
        if (tid < 256)
            async_copy16(ad + (size_t)(2048 + wbase) * 16,
                         asrc0 + (size_t)(2048 + tid) * 16);
#pragma unroll
        for (int it = 0; it < 9; ++it)
            async_copy16((char*)Blds + (size_t)(it * 512 + wbase) * 16,
                         bsrc0 + boff[it]);
        if (tid < 288) {
            const int4v vv = *(const int4v*)(bsrc0 + boff[9]);
            *(int4v*)((char*)Blds + (size_t)(4608 + tid) * 16) = vv;
        }
    }
    __syncthreads();                        // drains DMA + writes

    int4v pvB[10];
#pragma unroll 1
    for (int icc = 0; icc < 8; ++icc) {
        const int cur = icc & 1;
        const char* Ab = (const char*)&Alds[cur][0];

        if (icc < 7) {
            // A(icc+1) DMA into idle buffer (async; hides under compute)
            const char* as = asrc0 + (size_t)(icc + 1) * 36864;
            char* ad = (char*)&Alds[cur ^ 1][0];
#pragma unroll
            for (int i = 0; i < 4; ++i)
                async_copy16(ad + (size_t)(i * 512 + wbase) * 16,
                             as + (size_t)(i * 512 + tid) * 16);
            if (tid < 256)
                async_copy16(ad + (size_t)(2048 + wbase) * 16,
                             as + (size_t)(2048 + tid) * 16);
            // B(icc+1) -> registers
            const char* bs = bsrc0 + (size_t)(icc + 1) * bstride;
#pragma unroll
            for (int it = 0; it < 9; ++it)
                pvB[it] = *(const int4v*)(bs + boff[it]);
            if (tid < 288) pvB[9] = *(const int4v*)(bs + boff[9]);
        }

        // ---- compute icc (same per-px order as rounds 2/3)
#pragma unroll
        for (int sx = 0; sx < 3; ++sx) {
            frag_u Bf[2][6];                // rows wr*4 .. wr*4+5, this sx column
#pragma unroll
            for (int t = 0; t < 2; ++t)
#pragma unroll
                for (int rr = 0; rr < 6; ++rr) {
                    int pos = (wr * 4 + rr) * 34 + (wc * 16 + l15 + sx);
                    const char* bp = (const char*)Blds + (size_t)pos * 128
                        + ((((t << 2) | quad) ^ (pos & 7)) << 4);
                    Bf[t][rr].v = *(const int4v*)bp;
                }
#pragma unroll
            for (int sy = 0; sy < 3; ++sy) {
                const int tap = sy * 3 + sx;
                frag_u Af[2][2];
#pragma unroll
                for (int t = 0; t < 2; ++t)
#pragma unroll
                    for (int mi = 0; mi < 2; ++mi) {
                        const char* ap = Ab
                            + (size_t)(tap * 32 + mi * 16) * 128 + aoff[t];
                        Af[t][mi].v = *(const int4v*)ap;
                    }
#pragma unroll
                for (int mi = 0; mi < 2; ++mi)
#pragma unroll
                    for (int nj = 0; nj < 4; ++nj) {
                        acc[mi][nj] = __builtin_amdgcn_mfma_f32_16x16x32_bf16(
                            Af[0][mi].s8, Bf[0][nj + sy].s8, acc[mi][nj], 0, 0, 0);
                        acc[mi][nj] = __builtin_amdgcn_mfma_f32_16x16x32_bf16(
                            Af[0][mi].s8, Bf[1][nj + sy].s8, acc[mi][nj], 0, 0, 0);
                        acc[mi][nj] = __builtin_amdgcn_mfma_f32_16x16x32_bf16(
                            Af[1][mi].s8, Bf[0][nj + sy].s8, acc[mi][nj], 0, 0, 0);
                    }
            }
        }

        // ---- write phase: pure ds_writes (A-DMA already long in flight)
        if (icc < 7) {
            __syncthreads();                // all frag reads of Blds complete
#pragma unroll
            for (int it = 0; it < 9; ++it)
                *(int4v*)((char*)Blds + (size_t)(it * 512 + tid) * 16) = pvB[it];
            if (tid < 288)
                *(int4v*)((char*)Blds + (size_t)(4608 + tid) * 16) = pvB[9];
            __syncthreads();                // drains B writes + A DMA
        }
    }

    // ---- epilogue: BN + ReLU.  C/D: col(l15)=px col, row(quad*4+r)=oc.
#pragma unroll
    for (int nj = 0; nj < 4; ++nj) {
        const int gy = ty + wr * 4 + nj, gx = tx + wc * 16 + l15;
#pragma unroll
        for (int mi = 0; mi < 2; ++mi)
#pragma unroll
            for (int r = 0; r < 4; ++r) {
                const int oc = oc0 + mi * 16 + quad * 4 + r;
                float v = acc[mi][nj][r] + b1[oc];
                v = (v - mean[oc]) * bns[oc] + beta[oc];
                y1[((size_t)(bb * COUT1 + oc)) * HWSZ + gy * IMG + gx] = fmaxf(v, 0.0f);
            }
    }
}

// ===========================================================================
// =======================  LEGACY PATH (ws fallback)  =======================
// ===========================================================================

__global__ void wpack_kernel(const float* __restrict__ w1, short* __restrict__ wpk) {
    int e = blockIdx.x * 256 + threadIdx.x;      // 12*8*9*32*64 = 1,769,472 exact
    int row = e >> 6, sp = e & 63;
    int ocl = row & 31;
    int tap = (row >> 5) % 9;
    int icc = (row / 288) & 7;
    int octile = row / 2304;
    int s = (sp >> 2) ^ (ocl & 15);              // logical slot
    int ql = s * 4 + (sp & 3);                   // logical short index 0..63
    int term = ql >> 5, icl = ql & 31;
    int oc = octile * 32 + ocl, ic = icc * 32 + icl;
    float a = w1[((size_t)oc * CIN + ic) * 9 + tap];
    unsigned short hi = f2bf(a);
    wpk[e] = (term == 0) ? (short)hi : (short)f2bf(a - bf2f(hi));
}

__global__ __launch_bounds__(256, 2) void conv1_mfma(
    const float* __restrict__ feat, const short* __restrict__ wpk,
    const float* __restrict__ b1, const float* __restrict__ gamma,
    const float* __restrict__ beta, const float* __restrict__ mean,
    const float* __restrict__ var, float* __restrict__ y1) {
    const int bid   = blockIdx.x;                 // 0..4799
    const int slot  = bid >> 3;                   // 0..599
    const int tile  = (bid & 7) + ((slot / 12) << 3);   // XCD-local tile set
    const int octile = slot - (slot / 12) * 12;   // 0..11
    const int bb = tile / 100, tt = tile % 100;
    const int ty = (tt / 10) * 16, tx = (tt % 10) * 16;
    const int oc0 = octile * 32;
    const int tid  = threadIdx.x;
    const int w    = tid >> 6;              // wave: px rows w*4..w*4+3
    const int lane = tid & 63;
    const int quad = lane >> 4;
    const int l15  = lane & 15;

    __shared__ short Alds[288 * 64];        // [tap*32+ocl][64 sh, perm'd] 36864 B
    __shared__ short Blds[324 * 68];        // [hy*18+hx][t0 32|t1 32|pad] 44064 B

    int aoff[2][2];
#pragma unroll
    for (int t = 0; t < 2; ++t)
#pragma unroll
        for (int h = 0; h < 2; ++h)
            aoff[t][h] = l15 * 128 + (((t * 8 + quad * 2 + h) ^ l15) * 8);

    f32x4 acc[2][4];
#pragma unroll
    for (int mi = 0; mi < 2; ++mi)
#pragma unroll
        for (int nj = 0; nj < 4; ++nj) acc[mi][nj] = (f32x4){0.f, 0.f, 0.f, 0.f};

    const int4v* asrc_base = (const int4v*)wpk + (size_t)(octile * 8) * 2304;
    unsigned* Bd = (unsigned*)Blds;

    // B prefetch registers: 21 iters x 2 floats
    float pv0[21], pv1[21];

    // ---- prefetch chunk 0
#pragma unroll
    for (int ii = 0; ii < 21; ++ii) {
        int i = tid + ii * 256;
        if (i < 5184) {
            int icp = i / 324, hp = i - icp * 324;
            int hy = hp / 18, hx = hp - hy * 18;
            int gy = ty + hy - 1, gx = tx + hx - 1;
            bool valid = ((unsigned)gy < IMG) && ((unsigned)gx < IMG);
            const float* fs = feat + ((size_t)(bb * CIN + icp * 2)) * HWSZ
                                   + (valid ? (gy * IMG + gx) : 0);
            pv0[ii] = valid ? fs[0]    : 0.0f;
            pv1[ii] = valid ? fs[HWSZ] : 0.0f;
        }
    }

#pragma unroll 1
    for (int icc = 0; icc < 8; ++icc) {
        __syncthreads();                    // prev chunk's frag reads complete
        // ---- stage A: 36864 B = 2304 int4 (wpk is L2-hot)
        {
            const int4v* asrc = asrc_base + (size_t)icc * 2304;
            int4v* adst = (int4v*)Alds;
#pragma unroll
            for (int i = 0; i < 9; ++i)
                adst[tid + i * 256] = asrc[tid + i * 256];
        }
        // ---- write prefetched B: convert + split to LDS
#pragma unroll
        for (int ii = 0; ii < 21; ++ii) {
            int i = tid + ii * 256;
            if (i < 5184) {
                int icp = i / 324, hp = i - icp * 324;
                float v0 = pv0[ii], v1 = pv1[ii];
                unsigned short h0 = f2bf(v0), h1 = f2bf(v1);
                unsigned short m0 = f2bf(v0 - bf2f(h0)), m1 = f2bf(v1 - bf2f(h1));
                Bd[hp * 34 + icp]      = (unsigned)h0 | ((unsigned)h1 << 16);
                Bd[hp * 34 + 16 + icp] = (unsigned)m0 | ((unsigned)m1 << 16);
            }
        }
        __syncthreads();

        // ---- issue next chunk's B loads (overlap with compute below)
        if (icc < 7) {
#pragma unroll
            for (int ii = 0; ii < 21; ++ii) {
                int i = tid + ii * 256;
                if (i < 5184) {
                    int icp = i / 324, hp = i - icp * 324;
                    int hy = hp / 18, hx = hp - hy * 18;
                    int gy = ty + hy - 1, gx = tx + hx - 1;
                    bool valid = ((unsigned)gy < IMG) && ((unsigned)gx < IMG);
                    const float* fs = feat
                        + ((size_t)(bb * CIN + (icc + 1) * 32 + icp * 2)) * HWSZ
                        + (valid ? (gy * IMG + gx) : 0);
                    pv0[ii] = valid ? fs[0]    : 0.0f;
                    pv1[ii] = valid ? fs[HWSZ] : 0.0f;
                }
            }
        }

#pragma unroll
        for (int tap = 0; tap < 9; ++tap) {
            const int sy = tap / 3, sx = tap % 3;
            frag_u Af[2][2], Bf[2][4];
#pragma unroll
            for (int t = 0; t < 2; ++t) {
#pragma unroll
                for (int mi = 0; mi < 2; ++mi) {
                    const char* base = (const char*)Alds + (tap * 32 + mi * 16) * 128;
                    Af[t][mi].u[0] = *(const u64*)(base + aoff[t][0]);
                    Af[t][mi].u[1] = *(const u64*)(base + aoff[t][1]);
                }
#pragma unroll
                for (int nj = 0; nj < 4; ++nj) {
                    int pos = (w * 4 + nj + sy) * 18 + (l15 + sx);
                    const short* bp = &Blds[pos * 68 + t * 32 + quad * 8];
                    Bf[t][nj].u[0] = *(const u64*)bp;
                    Bf[t][nj].u[1] = *(const u64*)(bp + 4);
                }
            }
#pragma unroll
            for (int mi = 0; mi < 2; ++mi)
#pragma unroll
                for (int nj = 0; nj < 4; ++nj) {
                    acc[mi][nj] = __builtin_amdgcn_mfma_f32_16x16x32_bf16(
                        Af[0][mi].s8, Bf[0][nj].s8, acc[mi][nj], 0, 0, 0);
                    acc[mi][nj] = __builtin_amdgcn_mfma_f32_16x16x32_bf16(
                        Af[0][mi].s8, Bf[1][nj].s8, acc[mi][nj], 0, 0, 0);
                    acc[mi][nj] = __builtin_amdgcn_mfma_f32_16x16x32_bf16(
                        Af[1][mi].s8, Bf[0][nj].s8, acc[mi][nj], 0, 0, 0);
                    acc[mi][nj] = __builtin_amdgcn_mfma_f32_16x16x32_bf16(
                        Af[1][mi].s8, Bf[1][nj].s8, acc[mi][nj], 0, 0, 0);
                }
        }
    }

    // ---- epilogue: BN + ReLU.  C/D: col(l15)=px col, row(quad*4+r)=oc.
#pragma unroll
    for (int nj = 0; nj < 4; ++nj) {
        const int gy = ty + w * 4 + nj, gx = tx + l15;
#pragma unroll
        for (int mi = 0; mi < 2; ++mi)
#pragma unroll
            for (int r = 0; r < 4; ++r) {
                const int oc = oc0 + mi * 16 + quad * 4 + r;
                float v = acc[mi][nj][r] + b1[oc];
                v = (v - mean[oc]) * (gamma[oc] / sqrtf(var[oc] + 1e-5f)) + beta[oc];
                y1[((size_t)(bb * COUT1 + oc)) * HWSZ + gy * IMG + gx] = fmaxf(v, 0.0f);
            }
    }
}

// ===========================================================================
// ===========================  SHARED TAIL  =================================
// ===========================================================================

// ---------------------------------------------------------------------------
// conv2 v2: grouped 3x3, SEL channels only.  32x16 px tile, 2 px/thread,
// LDS [16][18][40], float2 tap reads, staging indices precomputed.
// ---------------------------------------------------------------------------
__global__ __launch_bounds__(256, 2) void conv2_kernel(
    const float* __restrict__ y1, const float* __restrict__ w2,
    const float* __restrict__ b2, float* __restrict__ out) {
    const int KH[6]   = {1, 1, 2, 1, 2, 4};
    const int REG[6]  = {OFF_LMAP, OFF_JMAP, OFF_JOFF, OFF_CMAP, OFF_COFF, OFF_LVEC};
    const int SIGF[6] = {1, 1, 0, 1, 0, 0};

    const int bz = blockIdx.z;
    const int b  = bz / 6;
    const int h  = bz % 6;
    const int k  = KH[h];
    const int tx = blockIdx.x * 32, ty = blockIdx.y * 16;
    const int lx = threadIdx.x, ly = threadIdx.y;   // lx: column pair, ly: row
    const int tid = ly * 16 + lx;

    __shared__ float tin[16][18][40];               // 46080 B; 34 cols used
    float* const tinf = &tin[0][0][0];
    float accv[4][2] = {{0.f,0.f},{0.f,0.f},{0.f,0.f},{0.f,0.f}};

    const float* yb = y1 + ((size_t)(b * COUT1 + h * 64)) * HWSZ;

    // staging slots: 18 rows x 34 cols = 612 elements, <=3 per thread
    bool sok[3], sval[3];
    int  soff[3], sidx[3];
#pragma unroll
    for (int j = 0; j < 3; ++j) {
        int idx = tid + j * 256;
        sok[j] = (idx < 612);
        int r = idx / 34, col = idx - r * 34;
        int gy = ty - 1 + r, gx = tx - 1 + col;
        sval[j] = sok[j] && ((unsigned)gy < (unsigned)IMG) && ((unsigned)gx < (unsigned)IMG);
        soff[j] = sval[j] ? (gy * IMG + gx) : 0;
        sidx[j] = r * 40 + col;
    }

    for (int ic0 = 0; ic0 < 64; ic0 += 16) {
        __syncthreads();
#pragma unroll
        for (int j = 0; j < 3; ++j) {
            if (sok[j]) {
                const float* yp = yb + (size_t)ic0 * HWSZ + soff[j];
                float* tp = tinf + sidx[j];
#pragma unroll 4
                for (int c = 0; c < 16; ++c)
                    tp[c * 720] = sval[j] ? yp[(size_t)c * HWSZ] : 0.0f;
            }
        }
        __syncthreads();

        const float* tb = tinf + ly * 40 + 2 * lx;
#pragma unroll 2
        for (int c = 0; c < 16; ++c) {
            const float* tc = tb + c * 720;
            float n[3][4];
#pragma unroll
            for (int r = 0; r < 3; ++r) {
                float2 u = *(const float2*)(tc + r * 40);
                float2 v = *(const float2*)(tc + r * 40 + 2);
                n[r][0] = u.x; n[r][1] = u.y; n[r][2] = v.x; n[r][3] = v.y;
            }
#pragma unroll
            for (int o = 0; o < 4; ++o) {
                if (o < k) {
                    const float* wp = w2 + ((size_t)((h * 4 + o) * 64 + (ic0 + c))) * 9;
                    float a0 = accv[o][0], a1 = accv[o][1];
#pragma unroll
                    for (int r = 0; r < 3; ++r) {
                        float w0 = wp[3*r], w1 = wp[3*r+1], w2v = wp[3*r+2];
                        a0 = fmaf(n[r][0], w0, a0);
                        a1 = fmaf(n[r][1], w0, a1);
                        a0 = fmaf(n[r][1], w1, a0);
                        a1 = fmaf(n[r][2], w1, a1);
                        a0 = fmaf(n[r][2], w2v, a0);
                        a1 = fmaf(n[r][3], w2v, a1);
                    }
                    accv[o][0] = a0; accv[o][1] = a1;
                }
            }
        }
    }

    const int p = (ty + ly) * IMG + tx + 2 * lx;
#pragma unroll
    for (int o = 0; o < 4; ++o) {
        if (o < k) {
            float v0 = accv[o][0] + b2[h * 4 + o];
            float v1 = accv[o][1] + b2[h * 4 + o];
            if (SIGF[h]) { v0 = sigmoidf(v0); v1 = sigmoidf(v1); }
            size_t base = (size_t)REG[h] + ((size_t)(b * k + o)) * HWSZ + p;
            out[base]     = v0;
            out[base + 1] = v1;
        }
    }
}

// ---------------------------------------------------------------------------
// Fused NMS + key-pack + per-chunk bitonic sort (descending).
// 32 blocks: arr = bid>>2 (0..3 jmap batches, 4..7 cmap batches), chunk=bid&3.
// Each block computes its 8192 keys in-register, sorts in LDS (skewed),
// writes the sorted chunk to jsort||csort (contiguous region).
// ---------------------------------------------------------------------------
#define SK64(i) ((i) + ((i) >> 4))
__global__ __launch_bounds__(1024) void sortnms_kernel(
    const float* __restrict__ out, u64* __restrict__ buf) {
    __shared__ u64 s[8192 + 512];
    const int bid = blockIdx.x;          // 0..31
    const int arr = bid >> 2, chunk = bid & 3;
    const bool isj = (arr < 4);
    const int b = arr & 3;
    const float* mp = out + (isj ? OFF_JMAP : OFF_CMAP) + (size_t)b * HWSZ;

    for (int i = threadIdx.x; i < 8192; i += 1024) {
        int p = chunk * 8192 + i;
        u64 key = 0ull;
        if (p < HWSZ) {
            float v = mp[p];
            float nv = v;
            if (isj) {
                const int x = p % IMG, y = p / IMG;
                float mx = v;
#pragma unroll
                for (int dy = -1; dy <= 1; ++dy)
#pragma unroll
                    for (int dx = -1; dx <= 1; ++dx) {
                        int nx = x + dx, ny = y + dy;
                        if (nx >= 0 && nx < IMG && ny >= 0 && ny < IMG)
                            mx = fmaxf(mx, mp[ny * IMG + nx]);
                    }
                nv = (v == mx) ? v : 0.0f;
            }
            key = ((u64)__float_as_uint(nv) << 32)
                | (u64)(0xFFFFFFFFu - (unsigned)p);
        }
        s[SK64(i)] = key;
    }
    for (int k = 2; k <= 8192; k <<= 1)
        for (int j = k >> 1; j > 0; j >>= 1) {
            __syncthreads();
            for (int t = threadIdx.x; t < 4096; t += 1024) {
                int i = ((t & ~(j - 1)) << 1) | (t & (j - 1));
                int l = i | j;
                bool desc = ((i & k) == 0);
                u64 x = s[SK64(i)], y = s[SK64(l)];
                if (desc ? (x < y) : (x > y)) { s[SK64(i)] = y; s[SK64(l)] = x; }
            }
        }
    __syncthreads();
    const size_t base = (size_t)bid * 8192;
    for (int i = threadIdx.x; i < 8192; i += 1024) buf[base + i] = s[SK64(i)];
}

// ---------------------------------------------------------------------------
// Exact top-K extraction from 4 desc-sorted chunks via rank-merge.
// ---------------------------------------------------------------------------
__device__ __forceinline__ int count_gt_desc(const u64* __restrict__ a, u64 e) {
    int cnt = 0;
#pragma unroll
    for (int st = 8192; st > 0; st >>= 1)
        if (cnt + st <= 8192 && a[cnt + st - 1] > e) cnt += st;
    return cnt;
}

__global__ void merge_topk_kernel(const u64* __restrict__ jsort,
                                  const u64* __restrict__ csort,
                                  u64* __restrict__ jm, u64* __restrict__ cm) {
    const int b = blockIdx.y;
    int t = blockIdx.x * 256 + threadIdx.x;
    const u64* src; u64* dst; int K, chunk, pos;
    if (t < 1200) {
        src = jsort + (size_t)b * 32768; dst = jm + (size_t)b * 300;
        K = 300; chunk = t / 300; pos = t - chunk * 300;
    } else {
        t -= 1200;
        if (t >= 20000) return;
        src = csort + (size_t)b * 32768; dst = cm + (size_t)b * 5000;
        K = 5000; chunk = t / 5000; pos = t - chunk * 5000;
    }
    u64 e = src[chunk * 8192 + pos];
    int rank = pos;
#pragma unroll
    for (int c = 0; c < 4; ++c)
        if (c != chunk) rank += count_gt_desc(src + c * 8192, e);
    if (rank < K) dst[rank] = e;
}

// Full-LDS bitonic sort, ascending, 8192 int keys (one array per block).
__global__ __launch_bounds__(1024) void sort32_lds(int* __restrict__ buf) {
    __shared__ int s[8192];
    int* a = buf + (size_t)blockIdx.x * 8192;
    for (int i = threadIdx.x; i < 8192; i += 1024) s[i] = a[i];
    for (int k = 2; k <= 8192; k <<= 1)
        for (int j = k >> 1; j > 0; j >>= 1) {
            __syncthreads();
            for (int t = threadIdx.x; t < 4096; t += 1024) {
                int i = ((t & ~(j - 1)) << 1) | (t & (j - 1));
                int l = i | j;
                bool asc = ((i & k) == 0);
                int x = s[i], y = s[l];
                if (asc ? (x > y) : (x < y)) { s[i] = y; s[l] = x; }
            }
        }
    __syncthreads();
    for (int i = threadIdx.x; i < 8192; i += 1024) a[i] = s[i];
}

// ---------------------------------------------------------------------------
// Lines (junction computation fused in: each block rebuilds the 300 junction
// coords/validity from jm + joff into LDS -- ~300 cheap ops, kills a launch).
// ---------------------------------------------------------------------------
__global__ void lines_kernel(const u64* __restrict__ cmk,
                             const u64* __restrict__ jmk,
                             const float* __restrict__ out,
                             int* __restrict__ lkeys) {
    const int b = blockIdx.y;
    const int t = blockIdx.x * 256 + threadIdx.x;

    __shared__ float jx[300], jy[300];
    __shared__ int jv[300];
    {
        const float* j0 = out + OFF_JOFF + (size_t)(b * 2) * HWSZ;
        const float* j1 = j0 + HWSZ;
        for (int i = threadIdx.x; i < 300; i += 256) {
            u64 key = jmk[(size_t)b * 300 + i];
            float score  = __uint_as_float((unsigned)(key >> 32));
            unsigned idx = 0xFFFFFFFFu - (unsigned)(key & 0xFFFFFFFFull);
            jx[i] = clip_coord((float)(idx % IMG) + j0[idx] + 0.5f);
            jy[i] = clip_coord((float)(idx / IMG) + j1[idx] + 0.5f);
            jv[i] = (score >= 0.008f) ? 1 : 0;
        }
    }
    __syncthreads();

    if (t >= 8192) return;
    if (t >= 5000) { lkeys[b * 8192 + t] = 0x7FFFFFFF; return; }

    u64 key = cmk[(size_t)b * 5000 + t];
    unsigned idx = 0xFFFFFFFFu - (unsigned)(key & 0xFFFFFFFFull);
    const float* c0 = out + OFF_COFF + (size_t)(b * 2) * HWSZ;
    const float* c1 = c0 + HWSZ;
    const float* lv = out + OFF_LVEC + (size_t)(b * 4) * HWSZ;

    float cx = (float)(idx % IMG) + c0[idx] + 0.5f;
    float cy = (float)(idx / IMG) + c1[idx] + 0.5f;
    float e0x = clip_coord(cx + lv[idx]);
    float e0y = clip_coord(cy + lv[HWSZ + idx]);
    float e1x = clip_coord(cx + lv[2 * HWSZ + idx]);
    float e1y = clip_coord(cy + lv[3 * HWSZ + idx]);

    float m1 = 1e18f, m2 = 1e18f;
    int i1 = 0, i2 = 0;
    for (int j = 0; j < 300; ++j) {
        if (jv[j]) {
            float dx = e0x - jx[j], dy = e0y - jy[j];
            float d = dx * dx + dy * dy;
            if (d < m1) { m1 = d; i1 = j; }
            dx = e1x - jx[j]; dy = e1y - jy[j];
            d = dx * dx + dy * dy;
            if (d < m2) { m2 = d; i2 = j; }
        }
    }
    int imin = min(i1, i2), imax = max(i1, i2);
    lkeys[b * 8192 + t] = (i1 != i2) ? (imin * 300 + imax) : BIGK;
}

// Dedup sorted keys -> line segments + mask.  Junction coords recomputed
// from jm + joff (identical expressions -> bitwise-same values).
__global__ void finalize_kernel(const int* __restrict__ lkeys,
                                const u64* __restrict__ jmk,
                                float* __restrict__ out) {
    const int b = blockIdx.y;
    const int t = blockIdx.x * 256 + threadIdx.x;
    if (t >= 5000) return;
    const int* lk = lkeys + b * 8192;
    int sk = lk[t];
    bool first = ((t == 0) || (sk != lk[t - 1])) && (sk < BIGK);
    int a  = first ? sk / 300 : 0;
    int bb = first ? sk % 300 : 0;
    const float* j0 = out + OFF_JOFF + (size_t)(b * 2) * HWSZ;
    const float* j1 = j0 + HWSZ;
    u64 ka = jmk[(size_t)b * 300 + a];
    u64 kb = jmk[(size_t)b * 300 + bb];
    unsigned ia = 0xFFFFFFFFu - (unsigned)(ka & 0xFFFFFFFFull);
    unsigned ib = 0xFFFFFFFFu - (unsigned)(kb & 0xFFFFFFFFull);
    float p0x = clip_coord((float)(ia % IMG) + j0[ia] + 0.5f);
    float p0y = clip_coord((float)(ia / IMG) + j1[ia] + 0.5f);
    float p1x = clip_coord((float)(ib % IMG) + j0[ib] + 0.5f);
    float p1y = clip_coord((float)(ib / IMG) + j1[ib] + 0.5f);
    if (p0y > p1y) {
        float tx = p0x; p0x = p1x; p1x = tx;
        float ty = p0y; p0y = p1y; p1y = ty;
    }
    size_t base = OFF_LOI + (size_t)(b * 5000 + t) * 4;
    out[base]     = p0x;
    out[base + 1] = p0y;
    out[base + 2] = p1x;
    out[base + 3] = p1y;
    out[OFF_MASK + b * 5000 + t] = first ? 1.0f : 0.0f;
}

extern "C" void kernel_launch(void* const* d_in, const int* in_sizes, int n_in,
                              void* d_out, int out_size, void* d_ws, size_t ws_size,
                              hipStream_t stream) {
    const float* feat  = (const float*)d_in[0];
    const float* w1    = (const float*)d_in[1];
    const float* b1    = (const float*)d_in[2];
    const float* gamma = (const float*)d_in[3];
    const float* beta  = (const float*)d_in[4];
    const float* mean  = (const float*)d_in[5];
    const float* var   = (const float*)d_in[6];
    const float* w2    = (const float*)d_in[7];
    const float* b2    = (const float*)d_in[8];
    float* out = (float*)d_out;
    char*  ws  = (char*)d_ws;

    if (ws_size < WS_NEED_MIN) return;

    float* y1 = (float*)(ws + WS_Y1);
    u64* jsort = (u64*)(ws + WS_JSORT);
    int* lkeys  = (int*)(ws + WS_LKEY);
    u64* csort = (u64*)(ws + WS_CSORT);
    short* wpk = (short*)(ws + WS_WPK);
    float* bns = (float*)(ws + WS_BNS);
    u64* jm    = (u64*)(ws + WS_JM);
    u64* cm    = (u64*)(ws + WS_CM);
    short* fpk = (short*)(ws + WS_FPK);

    if (ws_size >= WS_NEED_PK) {
        // 0. fused prep: wpack + bnscale + pack_feat (one launch)
        prep_kernel<<<dim3(20035), dim3(256), 0, stream>>>(
            w1, wpk, gamma, var, bns, feat, fpk);
        // 1. conv1 + BN + ReLU: 16x32 tile, A-dbuf pipelined MFMA
        conv1_mfma_pk<<<dim3(2400), dim3(512), 0, stream>>>(
            fpk, wpk, b1, bns, beta, mean, y1);
    } else {
        // fallback: legacy path (workspace too small for fpk)
        wpack_kernel<<<dim3(6912), dim3(256), 0, stream>>>(w1, wpk);
        conv1_mfma<<<dim3(4800), dim3(256), 0, stream>>>(
            feat, wpk, b1, gamma, beta, mean, var, y1);
    }

    // 2. conv2 (grouped, SEL channels only) -> maps in d_out
    conv2_kernel<<<dim3(5, 10, NB * 6), dim3(16, 16), 0, stream>>>(y1, w2, b2, out);

    // 3. fused NMS + key-pack + chunk sort (jsort||csort contiguous)
    sortnms_kernel<<<dim3(32), dim3(1024), 0, stream>>>(out, jsort);

    // 4. exact top-300 / top-5000 by rank-merge of sorted chunks
    merge_topk_kernel<<<dim3(83, NB), dim3(256), 0, stream>>>(jsort, csort, jm, cm);

    // 5. line keys (junctions rebuilt in-block from jm)
    lines_kernel<<<dim3(32, NB), dim3(256), 0, stream>>>(cm, jm, out, lkeys);

    // 6. sort line keys ascending (full LDS)
    sort32_lds<<<dim3(NB), dim3(1024), 0, stream>>>(lkeys);

    // 7. dedup + emit loi/mask (junction coords recomputed from jm)
    finalize_kernel<<<dim3(20, NB), dim3(256), 0, stream>>>(lkeys, jm, out);
}

// Round 6
// 945.116 us; speedup vs baseline: 1.0642x; 1.0642x over previous
//
#include <hip/hip_runtime.h>
#include <math.h>

#define IMG   160
#define HWSZ  25600
#define NB    4
#define CIN   256
#define COUT1 384
#define BIGK  90000

// output offsets (in floats)
#define OFF_LMAP 0
#define OFF_JMAP 102400
#define OFF_JOFF 204800
#define OFF_CMAP 409600
#define OFF_COFF 512000
#define OFF_LVEC 716800
#define OFF_LOI  1126400
#define OFF_MASK 1206400

// workspace offsets (bytes)
static const size_t WS_Y1    = 0;
static const size_t WS_JSORT = (size_t)NB * COUT1 * HWSZ * 4;            // 157286400
static const size_t WS_CSORT = WS_JSORT + (size_t)NB * 32768 * 8;        // contiguous!
static const size_t WS_JUNC  = WS_CSORT + (size_t)NB * 32768 * 8;
static const size_t WS_JVAL  = WS_JUNC + (size_t)NB * 300 * 2 * 4;
static const size_t WS_LKEY  = WS_JVAL + (size_t)NB * 300 * 4;
static const size_t WS_WPK   = WS_LKEY + (size_t)NB * 8192 * 4;
// Wpack: 12 octiles * 8 icc * 9 taps * 32 ocl * 64 shorts * 2 B = 3,538,944
static const size_t WS_AFTER_WPK = WS_WPK + (size_t)12 * 8 * 9 * 32 * 64 * 2;
static const size_t WS_BNS   = WS_AFTER_WPK;                             // 384 f32
static const size_t WS_JM    = WS_BNS + 384 * 4;                         // NB*300 u64
static const size_t WS_CM    = WS_JM + (size_t)NB * 300 * 8;             // NB*5000 u64
static const size_t WS_FPK   = WS_CM + (size_t)NB * 5000 * 8;
static const size_t WS_NEED_MIN = WS_FPK;                                // legacy floor
// packed feat: [b][icc 8][py 162][px 162][128 B]  (zero border, slot-swizzled)
static const size_t WS_NEED_PK = WS_FPK + (size_t)NB * 8 * 162 * 162 * 128;  // ~258 MB

typedef unsigned long long u64;
typedef __attribute__((ext_vector_type(8))) short short8;
typedef __attribute__((ext_vector_type(4))) float f32x4;
typedef __attribute__((ext_vector_type(4))) int int4v;

union frag_u { short8 s8; u64 u[2]; int4v v; };

__device__ __forceinline__ float clip_coord(float v) {
    return fminf(fmaxf(v, 0.0f), 159.9999f);
}
__device__ __forceinline__ float sigmoidf(float v) {
    return 1.0f / (1.0f + expf(-v));
}
__device__ __forceinline__ unsigned short f2bf(float f) {   // RNE
    unsigned u = __float_as_uint(f);
    return (unsigned short)((u + 0x7FFFu + ((u >> 16) & 1u)) >> 16);
}
__device__ __forceinline__ float bf2f(unsigned short h) {
    return __uint_as_float((unsigned)h << 16);
}

// async 16B global -> LDS (DMA). LDS dest must be wave-uniform base; HW adds lane*16.
__device__ __forceinline__ void async_copy16(void* lds, const void* g) {
    __builtin_amdgcn_global_load_lds(
        (const __attribute__((address_space(1))) unsigned int*)g,
        (__attribute__((address_space(3))) unsigned int*)lds, 16, 0, 0);
}

// ===========================================================================
// ============================  NEW (pk) PATH  ==============================
// ===========================================================================

// ---------------------------------------------------------------------------
// Fused preprocessing: wpack (blocks 0..6911) + bnscale (6912) +
// pack_feat (6913..20034).
// ---------------------------------------------------------------------------
__global__ __launch_bounds__(256) void prep_kernel(
    const float* __restrict__ w1, short* __restrict__ wpk,
    const float* __restrict__ gamma, const float* __restrict__ var,
    float* __restrict__ bns,
    const float* __restrict__ feat, short* __restrict__ fpk) {
    const int blk = blockIdx.x;
    const int tid = threadIdx.x;
    if (blk < 6912) {                        // ---- wpack
        int e = blk * 256 + tid;             // 1,769,472 exact
        int row = e >> 6, sp = e & 63;
        int ocl = row & 31;
        int tap = (row >> 5) % 9;
        int icc = (row / 288) & 7;
        int octile = row / 2304;
        int p16 = sp >> 3, j = sp & 7;
        int l16 = p16 ^ (ocl & 7);           // logical 16B slot
        int ql = l16 * 8 + j;                // logical short index 0..63
        int term = ql >> 5, icl = ql & 31;
        int oc = octile * 32 + ocl, ic = icc * 32 + icl;
        float a = w1[((size_t)oc * CIN + ic) * 9 + tap];
        unsigned short hi = f2bf(a);
        wpk[e] = (term == 0) ? (short)hi : (short)f2bf(a - bf2f(hi));
        return;
    }
    if (blk == 6912) {                       // ---- bnscale (bitwise-same expr)
        for (int i = tid; i < COUT1; i += 256)
            bns[i] = gamma[i] / sqrtf(var[i] + 1e-5f);
        return;
    }
    // ---- pack_feat
    const int c4  = (tid >> 4) & 3;                       // channel quarter 0..3
    const int r0  = (tid & 15) | (((tid >> 6) & 3) << 4); // 0..63
    const int rest = (blk - 6913) * 64 + r0;  // (b*8+icc)*26244 + py*162 + px
    const int px = rest % 162;
    const int t2 = rest / 162;
    const int py = t2 % 162;
    const int bi = t2 / 162;                 // b*8 + icc
    const int s  = (2 * py + px) & 7;
    const int gy = py - 1, gx = px - 1;
    const bool valid = ((unsigned)gy < (unsigned)IMG) && ((unsigned)gx < (unsigned)IMG);
    const float* fs = feat + (size_t)(bi * 32 + c4 * 8) * HWSZ
                           + (valid ? gy * IMG + gx : 0);
    unsigned hi4[4], lo4[4];
#pragma unroll
    for (int j2 = 0; j2 < 4; ++j2) {
        float va = valid ? fs[(size_t)(2 * j2) * HWSZ]     : 0.0f;
        float vb = valid ? fs[(size_t)(2 * j2 + 1) * HWSZ] : 0.0f;
        unsigned short ha = f2bf(va), hb = f2bf(vb);
        unsigned short la = f2bf(va - bf2f(ha)), lb = f2bf(vb - bf2f(hb));
        hi4[j2] = (unsigned)ha | ((unsigned)hb << 16);
        lo4[j2] = (unsigned)la | ((unsigned)lb << 16);
    }
    const int p0 = c4 ^ s;            // phys slot of logical l=c4 (term0)
    const int p1 = (c4 | 4) ^ s;      // phys slot of logical l=c4+4 (term1)
    int4v* base = (int4v*)(fpk + (size_t)rest * 64);
    base[p0] = (int4v){ (int)hi4[0], (int)hi4[1], (int)hi4[2], (int)hi4[3] };
    base[p1] = (int4v){ (int)lo4[0], (int)lo4[1], (int)lo4[2], (int)lo4[3] };
}

// ---------------------------------------------------------------------------
// conv1: ROUND-2 CHAMPION, verbatim (measured 394.7 us, MfmaUtil 66%).
// 16x16 px tile, 256 thr, 2 blocks/CU (cross-block overlap hides the per-icc
// DMA drain).  3-product bf16 split, sx-outer 6-row B reuse, conflict-free
// swizzled b128 reads.
// ---------------------------------------------------------------------------
__global__ __launch_bounds__(256, 2) void conv1_mfma_pk(
    const short* __restrict__ fpk, const short* __restrict__ wpk,
    const float* __restrict__ b1, const float* __restrict__ bns,
    const float* __restrict__ beta, const float* __restrict__ mean,
    float* __restrict__ y1) {
    const int bid   = blockIdx.x;                 // 0..4799
    const int slot  = bid >> 3;                   // 0..599
    const int tile  = (bid & 7) + ((slot / 12) << 3);   // XCD-local tile set
    const int octile = slot - (slot / 12) * 12;   // 0..11
    const int bb = tile / 100, tt = tile % 100;
    const int ty = (tt / 10) * 16, tx = (tt % 10) * 16;
    const int oc0 = octile * 32;
    const int tid  = threadIdx.x;
    const int w    = tid >> 6;              // wave: px rows w*4..w*4+3
    const int lane = tid & 63;
    const int quad = lane >> 4;
    const int l15  = lane & 15;
    const int wbase = tid & 192;            // w*64, wave-uniform

    __shared__ __align__(16) short Alds[288 * 64];   // 36864 B
    __shared__ __align__(16) short Blds[324 * 64];   // 41472 B

    int aoff[2];
#pragma unroll
    for (int t = 0; t < 2; ++t)
        aoff[t] = l15 * 128 + ((((t << 2) | quad) ^ (l15 & 7)) << 4);

    f32x4 acc[2][4];
#pragma unroll
    for (int mi = 0; mi < 2; ++mi)
#pragma unroll
        for (int nj = 0; nj < 4; ++nj) acc[mi][nj] = (f32x4){0.f, 0.f, 0.f, 0.f};

    const char* asrc0 = (const char*)wpk + (size_t)(octile * 8) * 36864;

#pragma unroll 1
    for (int icc = 0; icc < 8; ++icc) {
        __syncthreads();                    // prev iter's frag reads complete
        // ---- A DMA: 2304 x 16B chunks, exact 9 per thread, linear
        {
            const char* asrc = asrc0 + (size_t)icc * 36864;
#pragma unroll
            for (int i = 0; i < 9; ++i) {
                int k = i * 256 + tid;
                async_copy16((char*)Alds + (size_t)(i * 256 + wbase) * 16,
                             asrc + (size_t)k * 16);
            }
        }
        // ---- B DMA: 2592 x 16B chunks (18 rows x 144), 10 full + 32 rem
        {
            const char* bsrc = (const char*)fpk
                + (((size_t)(bb * 8 + icc) * 162 + ty) * 162 + tx) * 128;
#pragma unroll
            for (int it = 0; it < 10; ++it) {
                int k = it * 256 + tid;
                int hy = (int)((unsigned)k / 144u);
                int r  = k - hy * 144;
                async_copy16((char*)Blds + (size_t)(it * 256 + wbase) * 16,
                             bsrc + (size_t)hy * (162 * 128) + (size_t)r * 16);
            }
            if (tid < 32) {                 // chunks 2560..2591: hy=17, r=112..143
                const int4v vv = *(const int4v*)(bsrc + (size_t)17 * (162 * 128)
                                                 + (size_t)(112 + tid) * 16);
                *(int4v*)((char*)Blds + (size_t)(2560 + tid) * 16) = vv;
            }
        }
        __syncthreads();                    // compiler drains vmcnt/lgkmcnt here

#pragma unroll
        for (int sx = 0; sx < 3; ++sx) {
            frag_u Bf[2][6];                // rows w*4 .. w*4+5, this sx column
#pragma unroll
            for (int t = 0; t < 2; ++t)
#pragma unroll
                for (int rr = 0; rr < 6; ++rr) {
                    int pos = (w * 4 + rr) * 18 + (l15 + sx);
                    const char* bp = (const char*)Blds + (size_t)pos * 128
                        + ((((t << 2) | quad) ^ (pos & 7)) << 4);
                    Bf[t][rr].v = *(const int4v*)bp;
                }
#pragma unroll
            for (int sy = 0; sy < 3; ++sy) {
                const int tap = sy * 3 + sx;
                frag_u Af[2][2];
#pragma unroll
                for (int t = 0; t < 2; ++t)
#pragma unroll
                    for (int mi = 0; mi < 2; ++mi) {
                        const char* ap = (const char*)Alds
                            + (size_t)(tap * 32 + mi * 16) * 128 + aoff[t];
                        Af[t][mi].v = *(const int4v*)ap;
                    }
#pragma unroll
                for (int mi = 0; mi < 2; ++mi)
#pragma unroll
                    for (int nj = 0; nj < 4; ++nj) {
                        acc[mi][nj] = __builtin_amdgcn_mfma_f32_16x16x32_bf16(
                            Af[0][mi].s8, Bf[0][nj + sy].s8, acc[mi][nj], 0, 0, 0);
                        acc[mi][nj] = __builtin_amdgcn_mfma_f32_16x16x32_bf16(
                            Af[0][mi].s8, Bf[1][nj + sy].s8, acc[mi][nj], 0, 0, 0);
                        acc[mi][nj] = __builtin_amdgcn_mfma_f32_16x16x32_bf16(
                            Af[1][mi].s8, Bf[0][nj + sy].s8, acc[mi][nj], 0, 0, 0);
                    }
            }
        }
    }

    // ---- epilogue: BN + ReLU.  C/D: col(l15)=px col, row(quad*4+r)=oc.
#pragma unroll
    for (int nj = 0; nj < 4; ++nj) {
        const int gy = ty + w * 4 + nj, gx = tx + l15;
#pragma unroll
        for (int mi = 0; mi < 2; ++mi)
#pragma unroll
            for (int r = 0; r < 4; ++r) {
                const int oc = oc0 + mi * 16 + quad * 4 + r;
                float v = acc[mi][nj][r] + b1[oc];
                v = (v - mean[oc]) * bns[oc] + beta[oc];
                y1[((size_t)(bb * COUT1 + oc)) * HWSZ + gy * IMG + gx] = fmaxf(v, 0.0f);
            }
    }
}

// ===========================================================================
// =======================  LEGACY PATH (ws fallback)  =======================
// ===========================================================================

__global__ void wpack_kernel(const float* __restrict__ w1, short* __restrict__ wpk) {
    int e = blockIdx.x * 256 + threadIdx.x;      // 12*8*9*32*64 = 1,769,472 exact
    int row = e >> 6, sp = e & 63;
    int ocl = row & 31;
    int tap = (row >> 5) % 9;
    int icc = (row / 288) & 7;
    int octile = row / 2304;
    int s = (sp >> 2) ^ (ocl & 15);              // logical slot
    int ql = s * 4 + (sp & 3);                   // logical short index 0..63
    int term = ql >> 5, icl = ql & 31;
    int oc = octile * 32 + ocl, ic = icc * 32 + icl;
    float a = w1[((size_t)oc * CIN + ic) * 9 + tap];
    unsigned short hi = f2bf(a);
    wpk[e] = (term == 0) ? (short)hi : (short)f2bf(a - bf2f(hi));
}

__global__ __launch_bounds__(256, 2) void conv1_mfma(
    const float* __restrict__ feat, const short* __restrict__ wpk,
    const float* __restrict__ b1, const float* __restrict__ gamma,
    const float* __restrict__ beta, const float* __restrict__ mean,
    const float* __restrict__ var, float* __restrict__ y1) {
    const int bid   = blockIdx.x;                 // 0..4799
    const int slot  = bid >> 3;                   // 0..599
    const int tile  = (bid & 7) + ((slot / 12) << 3);   // XCD-local tile set
    const int octile = slot - (slot / 12) * 12;   // 0..11
    const int bb = tile / 100, tt = tile % 100;
    const int ty = (tt / 10) * 16, tx = (tt % 10) * 16;
    const int oc0 = octile * 32;
    const int tid  = threadIdx.x;
    const int w    = tid >> 6;              // wave: px rows w*4..w*4+3
    const int lane = tid & 63;
    const int quad = lane >> 4;
    const int l15  = lane & 15;

    __shared__ short Alds[288 * 64];        // [tap*32+ocl][64 sh, perm'd] 36864 B
    __shared__ short Blds[324 * 68];        // [hy*18+hx][t0 32|t1 32|pad] 44064 B

    int aoff[2][2];
#pragma unroll
    for (int t = 0; t < 2; ++t)
#pragma unroll
        for (int h = 0; h < 2; ++h)
            aoff[t][h] = l15 * 128 + (((t * 8 + quad * 2 + h) ^ l15) * 8);

    f32x4 acc[2][4];
#pragma unroll
    for (int mi = 0; mi < 2; ++mi)
#pragma unroll
        for (int nj = 0; nj < 4; ++nj) acc[mi][nj] = (f32x4){0.f, 0.f, 0.f, 0.f};

    const int4v* asrc_base = (const int4v*)wpk + (size_t)(octile * 8) * 2304;
    unsigned* Bd = (unsigned*)Blds;

    // B prefetch registers: 21 iters x 2 floats
    float pv0[21], pv1[21];

    // ---- prefetch chunk 0
#pragma unroll
    for (int ii = 0; ii < 21; ++ii) {
        int i = tid + ii * 256;
        if (i < 5184) {
            int icp = i / 324, hp = i - icp * 324;
            int hy = hp / 18, hx = hp - hy * 18;
            int gy = ty + hy - 1, gx = tx + hx - 1;
            bool valid = ((unsigned)gy < IMG) && ((unsigned)gx < IMG);
            const float* fs = feat + ((size_t)(bb * CIN + icp * 2)) * HWSZ
                                   + (valid ? (gy * IMG + gx) : 0);
            pv0[ii] = valid ? fs[0]    : 0.0f;
            pv1[ii] = valid ? fs[HWSZ] : 0.0f;
        }
    }

#pragma unroll 1
    for (int icc = 0; icc < 8; ++icc) {
        __syncthreads();                    // prev chunk's frag reads complete
        // ---- stage A: 36864 B = 2304 int4 (wpk is L2-hot)
        {
            const int4v* asrc = asrc_base + (size_t)icc * 2304;
            int4v* adst = (int4v*)Alds;
#pragma unroll
            for (int i = 0; i < 9; ++i)
                adst[tid + i * 256] = asrc[tid + i * 256];
        }
        // ---- write prefetched B: convert + split to LDS
#pragma unroll
        for (int ii = 0; ii < 21; ++ii) {
            int i = tid + ii * 256;
            if (i < 5184) {
                int icp = i / 324, hp = i - icp * 324;
                float v0 = pv0[ii], v1 = pv1[ii];
                unsigned short h0 = f2bf(v0), h1 = f2bf(v1);
                unsigned short m0 = f2bf(v0 - bf2f(h0)), m1 = f2bf(v1 - bf2f(h1));
                Bd[hp * 34 + icp]      = (unsigned)h0 | ((unsigned)h1 << 16);
                Bd[hp * 34 + 16 + icp] = (unsigned)m0 | ((unsigned)m1 << 16);
            }
        }
        __syncthreads();

        // ---- issue next chunk's B loads (overlap with compute below)
        if (icc < 7) {
#pragma unroll
            for (int ii = 0; ii < 21; ++ii) {
                int i = tid + ii * 256;
                if (i < 5184) {
                    int icp = i / 324, hp = i - icp * 324;
                    int hy = hp / 18, hx = hp - hy * 18;
                    int gy = ty + hy - 1, gx = tx + hx - 1;
                    bool valid = ((unsigned)gy < IMG) && ((unsigned)gx < IMG);
                    const float* fs = feat
                        + ((size_t)(bb * CIN + (icc + 1) * 32 + icp * 2)) * HWSZ
                        + (valid ? (gy * IMG + gx) : 0);
                    pv0[ii] = valid ? fs[0]    : 0.0f;
                    pv1[ii] = valid ? fs[HWSZ] : 0.0f;
                }
            }
        }

#pragma unroll
        for (int tap = 0; tap < 9; ++tap) {
            const int sy = tap / 3, sx = tap % 3;
            frag_u Af[2][2], Bf[2][4];
#pragma unroll
            for (int t = 0; t < 2; ++t) {
#pragma unroll
                for (int mi = 0; mi < 2; ++mi) {
                    const char* base = (const char*)Alds + (tap * 32 + mi * 16) * 128;
                    Af[t][mi].u[0] = *(const u64*)(base + aoff[t][0]);
                    Af[t][mi].u[1] = *(const u64*)(base + aoff[t][1]);
                }
#pragma unroll
                for (int nj = 0; nj < 4; ++nj) {
                    int pos = (w * 4 + nj + sy) * 18 + (l15 + sx);
                    const short* bp = &Blds[pos * 68 + t * 32 + quad * 8];
                    Bf[t][nj].u[0] = *(const u64*)bp;
                    Bf[t][nj].u[1] = *(const u64*)(bp + 4);
                }
            }
#pragma unroll
            for (int mi = 0; mi < 2; ++mi)
#pragma unroll
                for (int nj = 0; nj < 4; ++nj) {
                    acc[mi][nj] = __builtin_amdgcn_mfma_f32_16x16x32_bf16(
                        Af[0][mi].s8, Bf[0][nj].s8, acc[mi][nj], 0, 0, 0);
                    acc[mi][nj] = __builtin_amdgcn_mfma_f32_16x16x32_bf16(
                        Af[0][mi].s8, Bf[1][nj].s8, acc[mi][nj], 0, 0, 0);
                    acc[mi][nj] = __builtin_amdgcn_mfma_f32_16x16x32_bf16(
                        Af[1][mi].s8, Bf[0][nj].s8, acc[mi][nj], 0, 0, 0);
                    acc[mi][nj] = __builtin_amdgcn_mfma_f32_16x16x32_bf16(
                        Af[1][mi].s8, Bf[1][nj].s8, acc[mi][nj], 0, 0, 0);
                }
        }
    }

    // ---- epilogue: BN + ReLU.  C/D: col(l15)=px col, row(quad*4+r)=oc.
#pragma unroll
    for (int nj = 0; nj < 4; ++nj) {
        const int gy = ty + w * 4 + nj, gx = tx + l15;
#pragma unroll
        for (int mi = 0; mi < 2; ++mi)
#pragma unroll
            for (int r = 0; r < 4; ++r) {
                const int oc = oc0 + mi * 16 + quad * 4 + r;
                float v = acc[mi][nj][r] + b1[oc];
                v = (v - mean[oc]) * (gamma[oc] / sqrtf(var[oc] + 1e-5f)) + beta[oc];
                y1[((size_t)(bb * COUT1 + oc)) * HWSZ + gy * IMG + gx] = fmaxf(v, 0.0f);
            }
    }
}

// ===========================================================================
// ===========================  SHARED TAIL  =================================
// ===========================================================================

// ---------------------------------------------------------------------------
// conv2: grouped 3x3, SEL channels only.  32x16 px tile, 2 px/thread,
// LDS [16][18][40], float2 tap reads, staging indices precomputed.
// ---------------------------------------------------------------------------
__global__ __launch_bounds__(256, 2) void conv2_kernel(
    const float* __restrict__ y1, const float* __restrict__ w2,
    const float* __restrict__ b2, float* __restrict__ out) {
    const int KH[6]   = {1, 1, 2, 1, 2, 4};
    const int REG[6]  = {OFF_LMAP, OFF_JMAP, OFF_JOFF, OFF_CMAP, OFF_COFF, OFF_LVEC};
    const int SIGF[6] = {1, 1, 0, 1, 0, 0};

    const int bz = blockIdx.z;
    const int b  = bz / 6;
    const int h  = bz % 6;
    const int k  = KH[h];
    const int tx = blockIdx.x * 32, ty = blockIdx.y * 16;
    const int lx = threadIdx.x, ly = threadIdx.y;   // lx: column pair, ly: row
    const int tid = ly * 16 + lx;

    __shared__ float tin[16][18][40];               // 46080 B; 34 cols used
    float* const tinf = &tin[0][0][0];
    float accv[4][2] = {{0.f,0.f},{0.f,0.f},{0.f,0.f},{0.f,0.f}};

    const float* yb = y1 + ((size_t)(b * COUT1 + h * 64)) * HWSZ;

    // staging slots: 18 rows x 34 cols = 612 elements, <=3 per thread
    bool sok[3], sval[3];
    int  soff[3], sidx[3];
#pragma unroll
    for (int j = 0; j < 3; ++j) {
        int idx = tid + j * 256;
        sok[j] = (idx < 612);
        int r = idx / 34, col = idx - r * 34;
        int gy = ty - 1 + r, gx = tx - 1 + col;
        sval[j] = sok[j] && ((unsigned)gy < (unsigned)IMG) && ((unsigned)gx < (unsigned)IMG);
        soff[j] = sval[j] ? (gy * IMG + gx) : 0;
        sidx[j] = r * 40 + col;
    }

    for (int ic0 = 0; ic0 < 64; ic0 += 16) {
        __syncthreads();
#pragma unroll
        for (int j = 0; j < 3; ++j) {
            if (sok[j]) {
                const float* yp = yb + (size_t)ic0 * HWSZ + soff[j];
                float* tp = tinf + sidx[j];
#pragma unroll 4
                for (int c = 0; c < 16; ++c)
                    tp[c * 720] = sval[j] ? yp[(size_t)c * HWSZ] : 0.0f;
            }
        }
        __syncthreads();

        const float* tb = tinf + ly * 40 + 2 * lx;
#pragma unroll 2
        for (int c = 0; c < 16; ++c) {
            const float* tc = tb + c * 720;
            float n[3][4];
#pragma unroll
            for (int r = 0; r < 3; ++r) {
                float2 u = *(const float2*)(tc + r * 40);
                float2 v = *(const float2*)(tc + r * 40 + 2);
                n[r][0] = u.x; n[r][1] = u.y; n[r][2] = v.x; n[r][3] = v.y;
            }
#pragma unroll
            for (int o = 0; o < 4; ++o) {
                if (o < k) {
                    const float* wp = w2 + ((size_t)((h * 4 + o) * 64 + (ic0 + c))) * 9;
                    float a0 = accv[o][0], a1 = accv[o][1];
#pragma unroll
                    for (int r = 0; r < 3; ++r) {
                        float w0 = wp[3*r], w1 = wp[3*r+1], w2v = wp[3*r+2];
                        a0 = fmaf(n[r][0], w0, a0);
                        a1 = fmaf(n[r][1], w0, a1);
                        a0 = fmaf(n[r][1], w1, a0);
                        a1 = fmaf(n[r][2], w1, a1);
                        a0 = fmaf(n[r][2], w2v, a0);
                        a1 = fmaf(n[r][3], w2v, a1);
                    }
                    accv[o][0] = a0; accv[o][1] = a1;
                }
            }
        }
    }

    const int p = (ty + ly) * IMG + tx + 2 * lx;
#pragma unroll
    for (int o = 0; o < 4; ++o) {
        if (o < k) {
            float v0 = accv[o][0] + b2[h * 4 + o];
            float v1 = accv[o][1] + b2[h * 4 + o];
            if (SIGF[h]) { v0 = sigmoidf(v0); v1 = sigmoidf(v1); }
            size_t base = (size_t)REG[h] + ((size_t)(b * k + o)) * HWSZ + p;
            out[base]     = v0;
            out[base + 1] = v1;
        }
    }
}

// ---------------------------------------------------------------------------
// Fused NMS + key-pack + per-chunk bitonic sort (descending).
// ---------------------------------------------------------------------------
#define SK64(i) ((i) + ((i) >> 4))
__global__ __launch_bounds__(1024) void sortnms_kernel(
    const float* __restrict__ out, u64* __restrict__ buf) {
    __shared__ u64 s[8192 + 512];
    const int bid = blockIdx.x;          // 0..31
    const int arr = bid >> 2, chunk = bid & 3;
    const bool isj = (arr < 4);
    const int b = arr & 3;
    const float* mp = out + (isj ? OFF_JMAP : OFF_CMAP) + (size_t)b * HWSZ;

    for (int i = threadIdx.x; i < 8192; i += 1024) {
        int p = chunk * 8192 + i;
        u64 key = 0ull;
        if (p < HWSZ) {
            float v = mp[p];
            float nv = v;
            if (isj) {
                const int x = p % IMG, y = p / IMG;
                float mx = v;
#pragma unroll
                for (int dy = -1; dy <= 1; ++dy)
#pragma unroll
                    for (int dx = -1; dx <= 1; ++dx) {
                        int nx = x + dx, ny = y + dy;
                        if (nx >= 0 && nx < IMG && ny >= 0 && ny < IMG)
                            mx = fmaxf(mx, mp[ny * IMG + nx]);
                    }
                nv = (v == mx) ? v : 0.0f;
            }
            key = ((u64)__float_as_uint(nv) << 32)
                | (u64)(0xFFFFFFFFu - (unsigned)p);
        }
        s[SK64(i)] = key;
    }
    for (int k = 2; k <= 8192; k <<= 1)
        for (int j = k >> 1; j > 0; j >>= 1) {
            __syncthreads();
            for (int t = threadIdx.x; t < 4096; t += 1024) {
                int i = ((t & ~(j - 1)) << 1) | (t & (j - 1));
                int l = i | j;
                bool desc = ((i & k) == 0);
                u64 x = s[SK64(i)], y = s[SK64(l)];
                if (desc ? (x < y) : (x > y)) { s[SK64(i)] = y; s[SK64(l)] = x; }
            }
        }
    __syncthreads();
    const size_t base = (size_t)bid * 8192;
    for (int i = threadIdx.x; i < 8192; i += 1024) buf[base + i] = s[SK64(i)];
}

// ---------------------------------------------------------------------------
// Exact top-K extraction from 4 desc-sorted chunks via rank-merge.
// ---------------------------------------------------------------------------
__device__ __forceinline__ int count_gt_desc(const u64* __restrict__ a, u64 e) {
    int cnt = 0;
#pragma unroll
    for (int st = 8192; st > 0; st >>= 1)
        if (cnt + st <= 8192 && a[cnt + st - 1] > e) cnt += st;
    return cnt;
}

__global__ void merge_topk_kernel(const u64* __restrict__ jsort,
                                  const u64* __restrict__ csort,
                                  u64* __restrict__ jm, u64* __restrict__ cm) {
    const int b = blockIdx.y;
    int t = blockIdx.x * 256 + threadIdx.x;
    const u64* src; u64* dst; int K, chunk, pos;
    if (t < 1200) {
        src = jsort + (size_t)b * 32768; dst = jm + (size_t)b * 300;
        K = 300; chunk = t / 300; pos = t - chunk * 300;
    } else {
        t -= 1200;
        if (t >= 20000) return;
        src = csort + (size_t)b * 32768; dst = cm + (size_t)b * 5000;
        K = 5000; chunk = t / 5000; pos = t - chunk * 5000;
    }
    u64 e = src[chunk * 8192 + pos];
    int rank = pos;
#pragma unroll
    for (int c = 0; c < 4; ++c)
        if (c != chunk) rank += count_gt_desc(src + c * 8192, e);
    if (rank < K) dst[rank] = e;
}

// ---------------------------------------------------------------------------
// Lines (junction computation fused in from jm).
// ---------------------------------------------------------------------------
__global__ void lines_kernel(const u64* __restrict__ cmk,
                             const u64* __restrict__ jmk,
                             const float* __restrict__ out,
                             int* __restrict__ lkeys) {
    const int b = blockIdx.y;
    const int t = blockIdx.x * 256 + threadIdx.x;

    __shared__ float jx[300], jy[300];
    __shared__ int jv[300];
    {
        const float* j0 = out + OFF_JOFF + (size_t)(b * 2) * HWSZ;
        const float* j1 = j0 + HWSZ;
        for (int i = threadIdx.x; i < 300; i += 256) {
            u64 key = jmk[(size_t)b * 300 + i];
            float score  = __uint_as_float((unsigned)(key >> 32));
            unsigned idx = 0xFFFFFFFFu - (unsigned)(key & 0xFFFFFFFFull);
            jx[i] = clip_coord((float)(idx % IMG) + j0[idx] + 0.5f);
            jy[i] = clip_coord((float)(idx / IMG) + j1[idx] + 0.5f);
            jv[i] = (score >= 0.008f) ? 1 : 0;
        }
    }
    __syncthreads();

    if (t >= 8192) return;
    if (t >= 5000) { lkeys[b * 8192 + t] = 0x7FFFFFFF; return; }

    u64 key = cmk[(size_t)b * 5000 + t];
    unsigned idx = 0xFFFFFFFFu - (unsigned)(key & 0xFFFFFFFFull);
    const float* c0 = out + OFF_COFF + (size_t)(b * 2) * HWSZ;
    const float* c1 = c0 + HWSZ;
    const float* lv = out + OFF_LVEC + (size_t)(b * 4) * HWSZ;

    float cx = (float)(idx % IMG) + c0[idx] + 0.5f;
    float cy = (float)(idx / IMG) + c1[idx] + 0.5f;
    float e0x = clip_coord(cx + lv[idx]);
    float e0y = clip_coord(cy + lv[HWSZ + idx]);
    float e1x = clip_coord(cx + lv[2 * HWSZ + idx]);
    float e1y = clip_coord(cy + lv[3 * HWSZ + idx]);

    float m1 = 1e18f, m2 = 1e18f;
    int i1 = 0, i2 = 0;
    for (int j = 0; j < 300; ++j) {
        if (jv[j]) {
            float dx = e0x - jx[j], dy = e0y - jy[j];
            float d = dx * dx + dy * dy;
            if (d < m1) { m1 = d; i1 = j; }
            dx = e1x - jx[j]; dy = e1y - jy[j];
            d = dx * dx + dy * dy;
            if (d < m2) { m2 = d; i2 = j; }
        }
    }
    int imin = min(i1, i2), imax = max(i1, i2);
    lkeys[b * 8192 + t] = (i1 != i2) ? (imin * 300 + imax) : BIGK;
}

// ---------------------------------------------------------------------------
// Fused sort32 + finalize: bitonic-sort the 8192 line keys ascending in LDS,
// then dedup + emit loi/mask directly from LDS (no global round-trip).
// ---------------------------------------------------------------------------
__global__ __launch_bounds__(1024) void sortfin_kernel(
    const int* __restrict__ lkeys, const u64* __restrict__ jmk,
    float* __restrict__ out) {
    __shared__ int s[8192];
    const int b = blockIdx.x;
    const int* a = lkeys + (size_t)b * 8192;
    for (int i = threadIdx.x; i < 8192; i += 1024) s[i] = a[i];
    for (int k = 2; k <= 8192; k <<= 1)
        for (int j = k >> 1; j > 0; j >>= 1) {
            __syncthreads();
            for (int t = threadIdx.x; t < 4096; t += 1024) {
                int i = ((t & ~(j - 1)) << 1) | (t & (j - 1));
                int l = i | j;
                bool asc = ((i & k) == 0);
                int x = s[i], y = s[l];
                if (asc ? (x > y) : (x < y)) { s[i] = y; s[l] = x; }
            }
        }
    __syncthreads();

    const float* j0 = out + OFF_JOFF + (size_t)(b * 2) * HWSZ;
    const float* j1 = j0 + HWSZ;
    for (int t = threadIdx.x; t < 5000; t += 1024) {
        int sk = s[t];
        bool first = ((t == 0) || (sk != s[t - 1])) && (sk < BIGK);
        int aa = first ? sk / 300 : 0;
        int bb = first ? sk % 300 : 0;
        u64 ka = jmk[(size_t)b * 300 + aa];
        u64 kb = jmk[(size_t)b * 300 + bb];
        unsigned ia = 0xFFFFFFFFu - (unsigned)(ka & 0xFFFFFFFFull);
        unsigned ib = 0xFFFFFFFFu - (unsigned)(kb & 0xFFFFFFFFull);
        float p0x = clip_coord((float)(ia % IMG) + j0[ia] + 0.5f);
        float p0y = clip_coord((float)(ia / IMG) + j1[ia] + 0.5f);
        float p1x = clip_coord((float)(ib % IMG) + j0[ib] + 0.5f);
        float p1y = clip_coord((float)(ib / IMG) + j1[ib] + 0.5f);
        if (p0y > p1y) {
            float tx = p0x; p0x = p1x; p1x = tx;
            float ty = p0y; p0y = p1y; p1y = ty;
        }
        size_t base = OFF_LOI + (size_t)(b * 5000 + t) * 4;
        out[base]     = p0x;
        out[base + 1] = p0y;
        out[base + 2] = p1x;
        out[base + 3] = p1y;
        out[OFF_MASK + b * 5000 + t] = first ? 1.0f : 0.0f;
    }
}

extern "C" void kernel_launch(void* const* d_in, const int* in_sizes, int n_in,
                              void* d_out, int out_size, void* d_ws, size_t ws_size,
                              hipStream_t stream) {
    const float* feat  = (const float*)d_in[0];
    const float* w1    = (const float*)d_in[1];
    const float* b1    = (const float*)d_in[2];
    const float* gamma = (const float*)d_in[3];
    const float* beta  = (const float*)d_in[4];
    const float* mean  = (const float*)d_in[5];
    const float* var   = (const float*)d_in[6];
    const float* w2    = (const float*)d_in[7];
    const float* b2    = (const float*)d_in[8];
    float* out = (float*)d_out;
    char*  ws  = (char*)d_ws;

    if (ws_size < WS_NEED_MIN) return;

    float* y1 = (float*)(ws + WS_Y1);
    u64* jsort = (u64*)(ws + WS_JSORT);
    int* lkeys  = (int*)(ws + WS_LKEY);
    u64* csort = (u64*)(ws + WS_CSORT);
    short* wpk = (short*)(ws + WS_WPK);
    float* bns = (float*)(ws + WS_BNS);
    u64* jm    = (u64*)(ws + WS_JM);
    u64* cm    = (u64*)(ws + WS_CM);
    short* fpk = (short*)(ws + WS_FPK);

    if (ws_size >= WS_NEED_PK) {
        // 0. fused prep: wpack + bnscale + pack_feat (one launch)
        prep_kernel<<<dim3(20035), dim3(256), 0, stream>>>(
            w1, wpk, gamma, var, bns, feat, fpk);
        // 1. conv1 + BN + ReLU: round-2 champion structure
        conv1_mfma_pk<<<dim3(4800), dim3(256), 0, stream>>>(
            fpk, wpk, b1, bns, beta, mean, y1);
    } else {
        // fallback: legacy path (workspace too small for fpk)
        wpack_kernel<<<dim3(6912), dim3(256), 0, stream>>>(w1, wpk);
        conv1_mfma<<<dim3(4800), dim3(256), 0, stream>>>(
            feat, wpk, b1, gamma, beta, mean, var, y1);
    }

    // 2. conv2 (grouped, SEL channels only) -> maps in d_out
    conv2_kernel<<<dim3(5, 10, NB * 6), dim3(16, 16), 0, stream>>>(y1, w2, b2, out);

    // 3. fused NMS + key-pack + chunk sort (jsort||csort contiguous)
    sortnms_kernel<<<dim3(32), dim3(1024), 0, stream>>>(out, jsort);

    // 4. exact top-300 / top-5000 by rank-merge of sorted chunks
    merge_topk_kernel<<<dim3(83, NB), dim3(256), 0, stream>>>(jsort, csort, jm, cm);

    // 5. line keys (junctions rebuilt in-block from jm)
    lines_kernel<<<dim3(32, NB), dim3(256), 0, stream>>>(cm, jm, out, lkeys);

    // 6. fused sort + dedup + emit loi/mask
    sortfin_kernel<<<dim3(NB), dim3(1024), 0, stream>>>(lkeys, jm, out);
}